// Round 6
// baseline (895.635 us; speedup 1.0000x reference)
//
#include <hip/hip_runtime.h>

#define KF 128        // feature dim
#define NSUP 256      // support points per species
#define NSPEC 4
#define NTHREADS 768  // 12 waves, 1 block/CU (128 KB LDS)
#define NWAVES 12
#define GRID 256

typedef __bf16 bf16x8 __attribute__((ext_vector_type(8)));
typedef float  f32x4  __attribute__((ext_vector_type(4)));

// ---------------- build per-species Gram matrix ----------------
// G[s][c][k] = sum_m w[s][m] * sup[s][m][c] * sup[s][m][k]   (bf16 out, fp32 accum)
// grid = 4 species * 128 c-rows, 128 threads (one k each)

__global__ void k_buildG(const float* __restrict__ sup, const float* __restrict__ w,
                         __bf16* __restrict__ Gout) {
    const int s = blockIdx.x >> 7;
    const int c = blockIdx.x & 127;
    const int k = threadIdx.x;
    const float* S = sup + (size_t)s * NSUP * KF;
    const float* W = w + s * NSUP;
    float acc = 0.f;
    #pragma unroll 4
    for (int m = 0; m < NSUP; ++m)
        acc += W[m] * S[m * KF + c] * S[m * KF + k];
    Gout[((size_t)(s * 128 + c)) * 128 + k] = (__bf16)acc;
}

// ---------------- main kernel: sequential stream, no gather ----------------
// Per 32-atom wave-tile: Yt = G_s * X^T for all 4 species (MFMA, G-as-A from LDS,
// X-as-B from regs). D[c-row][atom-col]: lane(g,r) reg j = Y[atom at*16+r][c=16ct+4g+j].
// e_atom = sum_c x_c*y_c (species-predicated per lane), / ||x||^2, atomicAdd by sid.

__global__ __launch_bounds__(NTHREADS, 1) void k_main(
    const float* __restrict__ ps,
    const __bf16* __restrict__ Gws,
    const int* __restrict__ species,
    const int* __restrict__ sids,
    float* __restrict__ out,
    int n)
{
    __shared__ __align__(16) char Glds[NSPEC * 128 * 256];   // 128 KB

    // stage G -> LDS with XOR swizzle (byte ^= ((row&7)<<4))
    for (int f = threadIdx.x; f < 8192; f += NTHREADS) {
        int4 v = ((const int4*)Gws)[f];
        int dst = (f * 16) ^ ((((f >> 4) & 7)) << 4);
        *(int4*)(Glds + dst) = v;
    }
    __syncthreads();

    const int lane = threadIdx.x & 63;
    const int r = lane & 15, g = lane >> 4;
    const int gw = blockIdx.x * NWAVES + (threadIdx.x >> 6);
    const int gs = GRID * NWAVES;
    const int ntiles = (n + 31) / 32;
    const int swz = (r & 7) << 4;
    const int lbase = (r << 8) | (g << 4);

    if (gw >= ntiles) return;

    float4 pf[16];        // current tile rows (fp32): pf[at*8 + kk*2 + h]
    int spc[2], sid[2];

    // ---- prologue: tile gw ----
    {
        const int base = gw * 32;
        #pragma unroll
        for (int at = 0; at < 2; ++at) {
            int a = base + at * 16 + r;
            bool v = (a < n);
            int ra = v ? a : 0;
            spc[at] = v ? species[a] : -1;
            sid[at] = v ? sids[a] : 0;
            const float* src = ps + (size_t)ra * KF + g * 8;
            #pragma unroll
            for (int kk = 0; kk < 4; ++kk) {
                pf[at * 8 + kk * 2 + 0] = *(const float4*)(src + kk * 32);
                pf[at * 8 + kk * 2 + 1] = *(const float4*)(src + kk * 32 + 4);
            }
        }
    }

    for (int t = gw; t < ntiles; t += gs) {
        const int tn = t + gs;

        // ---- norms (fp32) ----
        float s0 = 0.f, s1 = 0.f;
        #pragma unroll
        for (int i = 0; i < 8; ++i) {
            float4 a = pf[i], b = pf[8 + i];
            s0 += a.x * a.x + a.y * a.y + a.z * a.z + a.w * a.w;
            s1 += b.x * b.x + b.y * b.y + b.z * b.z + b.w * b.w;
        }
        s0 += __shfl_xor(s0, 16); s0 += __shfl_xor(s0, 32);
        s1 += __shfl_xor(s1, 16); s1 += __shfl_xor(s1, 32);
        const float nn0 = s0, nn1 = s1;

        // ---- convert to B-fragments: bf[at][kk][t] = x[atom][kk*32 + 8g + t] ----
        bf16x8 bf[2][4];
        #pragma unroll
        for (int at = 0; at < 2; ++at)
            #pragma unroll
            for (int kk = 0; kk < 4; ++kk) {
                float4 a = pf[at * 8 + kk * 2], b = pf[at * 8 + kk * 2 + 1];
                bf16x8 v;
                v[0] = (__bf16)a.x; v[1] = (__bf16)a.y; v[2] = (__bf16)a.z; v[3] = (__bf16)a.w;
                v[4] = (__bf16)b.x; v[5] = (__bf16)b.y; v[6] = (__bf16)b.z; v[7] = (__bf16)b.w;
                bf[at][kk] = v;
            }

        // ---- prefetch next tile (covered by compute) ----
        int nspc[2] = {-1, -1}, nsid[2] = {0, 0};
        if (tn < ntiles) {
            const int base = tn * 32;
            #pragma unroll
            for (int at = 0; at < 2; ++at) {
                int a = base + at * 16 + r;
                bool v = (a < n);
                int ra = v ? a : 0;
                nspc[at] = v ? species[a] : -1;
                nsid[at] = v ? sids[a] : 0;
                const float* src = ps + (size_t)ra * KF + g * 8;
                #pragma unroll
                for (int kk = 0; kk < 4; ++kk) {
                    pf[at * 8 + kk * 2 + 0] = *(const float4*)(src + kk * 32);
                    pf[at * 8 + kk * 2 + 1] = *(const float4*)(src + kk * 32 + 4);
                }
            }
        }

        // ---- compute ----
        float e0 = 0.f, e1 = 0.f;
        #pragma unroll
        for (int ct = 0; ct < 8; ++ct) {
            // x in C-layout via 4-lane shuffle: need x[atom][16ct+4g+j] from
            // lane g' = 2(ct&1)+(g>>1), frag kk'=ct>>1, dwords 2(g&1), 2(g&1)+1
            const int srcl = (((ct & 1) * 2 + (g >> 1)) << 4) | r;
            int4 b0 = *(int4*)&bf[0][ct >> 1];
            int4 b1 = *(int4*)&bf[1][ct >> 1];
            int t00 = __shfl(b0.x, srcl), t01 = __shfl(b0.y, srcl);
            int t02 = __shfl(b0.z, srcl), t03 = __shfl(b0.w, srcl);
            int t10 = __shfl(b1.x, srcl), t11 = __shfl(b1.y, srcl);
            int t12 = __shfl(b1.z, srcl), t13 = __shfl(b1.w, srcl);
            const int lo0 = (g & 1) ? t02 : t00, hi0 = (g & 1) ? t03 : t01;
            const int lo1 = (g & 1) ? t12 : t10, hi1 = (g & 1) ? t13 : t11;
            const float x00 = __int_as_float(lo0 << 16);
            const float x01 = __int_as_float(lo0 & 0xffff0000);
            const float x02 = __int_as_float(hi0 << 16);
            const float x03 = __int_as_float(hi0 & 0xffff0000);
            const float x10 = __int_as_float(lo1 << 16);
            const float x11 = __int_as_float(lo1 & 0xffff0000);
            const float x12 = __int_as_float(hi1 << 16);
            const float x13 = __int_as_float(hi1 & 0xffff0000);

            #pragma unroll
            for (int s = 0; s < NSPEC; ++s) {
                f32x4 acc0 = (f32x4){0.f, 0.f, 0.f, 0.f};
                f32x4 acc1 = (f32x4){0.f, 0.f, 0.f, 0.f};
                #pragma unroll
                for (int kk = 0; kk < 4; ++kk) {
                    const int addr = ((s << 15) | (ct << 12) | (kk << 6) | lbase) ^ swz;
                    bf16x8 Af = *(const bf16x8*)(Glds + addr);
                    acc0 = __builtin_amdgcn_mfma_f32_16x16x32_bf16(Af, bf[0][kk], acc0, 0, 0, 0);
                    acc1 = __builtin_amdgcn_mfma_f32_16x16x32_bf16(Af, bf[1][kk], acc1, 0, 0, 0);
                }
                float d0 = x00 * acc0[0] + x01 * acc0[1] + x02 * acc0[2] + x03 * acc0[3];
                float d1 = x10 * acc1[0] + x11 * acc1[1] + x12 * acc1[2] + x13 * acc1[3];
                if (spc[0] == s) e0 += d0;
                if (spc[1] == s) e1 += d1;
            }
        }

        // ---- reduce over g-lanes and emit ----
        e0 += __shfl_xor(e0, 16); e0 += __shfl_xor(e0, 32);
        e1 += __shfl_xor(e1, 16); e1 += __shfl_xor(e1, 32);
        if (g == 0) {
            if (spc[0] >= 0 && nn0 > 0.f) atomicAdd(&out[sid[0]], e0 / nn0);
            if (spc[1] >= 0 && nn1 > 0.f) atomicAdd(&out[sid[1]], e1 / nn1);
        }

        spc[0] = nspc[0]; spc[1] = nspc[1];
        sid[0] = nsid[0]; sid[1] = nsid[1];
    }
}

// ---------------- slow-but-correct fallback (ws too small) ----------------

__global__ void k_fallback(const float* __restrict__ ps, const float* __restrict__ support,
                           const float* __restrict__ weights, const int* __restrict__ species,
                           const int* __restrict__ struct_ids, float* __restrict__ out, int n)
{
    int gw = (blockIdx.x * blockDim.x + threadIdx.x) >> 6;
    int lane = threadIdx.x & 63;
    int nw = (gridDim.x * blockDim.x) >> 6;
    for (int atom = gw; atom < n; atom += nw) {
        const float* row = ps + (size_t)atom * KF;
        float x0 = row[lane], x1 = row[lane + 64];
        float nsum = x0 * x0 + x1 * x1;
        for (int o = 32; o; o >>= 1) nsum += __shfl_xor(nsum, o);
        float iv2 = 1.0f / nsum;
        int s = species[atom];
        const float* sup = support + (size_t)s * NSUP * KF;
        const float* w = weights + (size_t)s * NSUP;
        float e = 0.f;
        for (int mm = 0; mm < 4; ++mm) {
            int m = lane + mm * 64;
            const float* srow = sup + (size_t)m * KF;
            float d = 0.f;
            for (int k = 0; k < KF; ++k) d += row[k] * srow[k];
            e += d * d * w[m];
        }
        for (int o = 32; o; o >>= 1) e += __shfl_xor(e, o);
        if (lane == 0) atomicAdd(&out[struct_ids[atom]], e * iv2);
    }
}

// ---------------- launch ----------------

extern "C" void kernel_launch(void* const* d_in, const int* in_sizes, int n_in,
                              void* d_out, int out_size, void* d_ws, size_t ws_size,
                              hipStream_t stream)
{
    const float* ps       = (const float*)d_in[0];
    const float* support  = (const float*)d_in[1];
    const float* weights  = (const float*)d_in[2];
    const int*   species  = (const int*)d_in[3];
    const int*   sids     = (const int*)d_in[4];
    float* out = (float*)d_out;
    const int n = in_sizes[0] / KF;

    hipMemsetAsync(d_out, 0, (size_t)out_size * sizeof(float), stream);

    const size_t gbytes = (size_t)NSPEC * 128 * 128 * sizeof(__bf16);   // 128 KB
    if (ws_size < gbytes) {
        k_fallback<<<2048, 256, 0, stream>>>(ps, support, weights, species, sids, out, n);
        return;
    }

    __bf16* Gws = (__bf16*)d_ws;
    k_buildG<<<NSPEC * 128, 128, 0, stream>>>(support, weights, Gws);
    k_main<<<GRID, NTHREADS, 0, stream>>>(ps, Gws, species, sids, out, n);
}